// Round 4
// baseline (125.643 us; speedup 1.0000x reference)
//
#include <hip/hip_runtime.h>
#include <math.h>
#include <stdint.h>

typedef __attribute__((ext_vector_type(8))) short bf16x8;
typedef __attribute__((ext_vector_type(4))) float f32x4;
typedef __attribute__((ext_vector_type(4))) int   i32x4;
typedef __attribute__((ext_vector_type(2))) int   i32x2;

#define NSITES 128
#define NBULK  126
#define BOND   64
#define BATCH  8192

#define WSITE     49152                             // 2v*3tm*2ks*4jt*1024B per site
#define WMASK_OFF ((size_t)NBULK * (size_t)WSITE)   // 6193152
#define WS_NEED   (WMASK_OFF + (size_t)BATCH * 16)

// LDS: env double-buffer + reduce scratch only (W never touches LDS now)
#define EBUF_SZ 12288        // 2g * 3tm * 16b * 128B
#define RED_OFF 24576
#define SMEM_SZ 25088

#define MFMA_BF16 __builtin_amdgcn_mfma_f32_16x16x32_bf16

// ============ prepass 1: split bulk into 3 trunc-bf16 planes, fragment-linear image ====
// granule(site,v,tm,ks,jt, lane l) at ((((v*3+tm)*2+ks)*4+jt)*1024 + l*16:
//   8 bf16 of W^T[j=jt*16+(l&15)][k=ks*32+(l>>4)*8 .. +7], plane v, term tm
__global__ void prep_w(const float* __restrict__ bulk, char* __restrict__ wsd) {
    const int s  = blockIdx.x;
    const int t  = threadIdx.x;          // 256
    const int jt = (t >> 6) & 3;
    const int l  = t & 63;
    const int j  = jt * 16 + (l & 15);
    const int kb0 = (l >> 4) * 8;
    const float* bs = bulk + (size_t)s * 8192;
    char* dsite = wsd + (size_t)s * WSITE;
    #pragma unroll
    for (int ks = 0; ks < 2; ++ks) {
        const int kb = ks * 32 + kb0;
        #pragma unroll
        for (int v = 0; v < 2; ++v) {
            uint h[3][8];
            #pragma unroll
            for (int e = 0; e < 8; ++e) {
                const float x = bs[(size_t)(kb + e) * 128 + v * 64 + j];
                const uint  u1 = __float_as_uint(x) & 0xffff0000u;
                const float r1 = x - __uint_as_float(u1);
                const uint  u2 = __float_as_uint(r1) & 0xffff0000u;
                const float r2 = r1 - __uint_as_float(u2);
                h[0][e] = u1; h[1][e] = u2;
                h[2][e] = __float_as_uint(r2) & 0xffff0000u;
            }
            #pragma unroll
            for (int tm = 0; tm < 3; ++tm) {
                i32x4 q;
                q.x = (int)((h[tm][0] >> 16) | (h[tm][1] & 0xffff0000u));
                q.y = (int)((h[tm][2] >> 16) | (h[tm][3] & 0xffff0000u));
                q.z = (int)((h[tm][4] >> 16) | (h[tm][5] & 0xffff0000u));
                q.w = (int)((h[tm][6] >> 16) | (h[tm][7] & 0xffff0000u));
                *(i32x4*)(dsite + ((((v*3+tm)*2+ks)*4 + jt) * 1024) + l * 16) = q;
            }
        }
    }
}

// ============ prepass 2: pack per-batch v bits into 4 uints via ballot ============
__global__ void prep_mask(const int* __restrict__ cfg, uint* __restrict__ msk) {
    const int w = threadIdx.x >> 6, l = threadIdx.x & 63;   // 256 thr = 4 waves
    const int b = blockIdx.x * 2 + (w >> 1);
    const int half = w & 1;
    int idx = half * 64 + l + 1;
    if (idx > 127) idx = 127;
    const int v = cfg[b * NSITES + idx];
    const unsigned long long bal = __ballot(v != 0);
    if (l == 0) {
        msk[b * 4 + half * 2]     = (uint)(bal & 0xffffffffu);
        msk[b * 4 + half * 2 + 1] = (uint)(bal >> 32);
    }
}

// ============ main kernel: 4 waves, W global->register double-buffered ============

#define PREFETCH_A(S, DBUF) do { \
    if ((S) < NBULK) { \
        const char* gp_ = ws + (size_t)(S) * WSITE; \
        _Pragma("unroll") for (int vv = 0; vv < 2; ++vv) \
        _Pragma("unroll") for (int tm = 0; tm < 3; ++tm) \
        _Pragma("unroll") for (int ks = 0; ks < 2; ++ks) \
            Areg[DBUF][vv][tm][ks] = *(const bf16x8*)(gp_ + aG[vv][tm][ks]); \
    } \
} while (0)

#define PUBLISH(PW) do { \
    uint pa_[3][4]; \
    _Pragma("unroll") \
    for (int r = 0; r < 4; ++r) { \
        const float x_ = eg0[r]; \
        const uint  u1_ = __float_as_uint(x_) & 0xffff0000u; \
        const float r1_ = x_ - __uint_as_float(u1_); \
        const uint  u2_ = __float_as_uint(r1_) & 0xffff0000u; \
        const float r2_ = r1_ - __uint_as_float(u2_); \
        pa_[0][r] = u1_; pa_[1][r] = u2_; \
        pa_[2][r] = __float_as_uint(r2_) & 0xffff0000u; \
    } \
    _Pragma("unroll") \
    for (int tm = 0; tm < 3; ++tm) { \
        i32x2 d_; \
        d_.x = (int)((pa_[tm][0] >> 16) | (pa_[tm][1] & 0xffff0000u)); \
        d_.y = (int)((pa_[tm][2] >> 16) | (pa_[tm][3] & 0xffff0000u)); \
        *(i32x2*)(smem + aW[PW] + tm * 2048) = d_; \
    } \
    _Pragma("unroll") \
    for (int r = 0; r < 4; ++r) { \
        const float x_ = eg1[r]; \
        const uint  u1_ = __float_as_uint(x_) & 0xffff0000u; \
        const float r1_ = x_ - __uint_as_float(u1_); \
        const uint  u2_ = __float_as_uint(r1_) & 0xffff0000u; \
        const float r2_ = r1_ - __uint_as_float(u2_); \
        pa_[0][r] = u1_; pa_[1][r] = u2_; \
        pa_[2][r] = __float_as_uint(r2_) & 0xffff0000u; \
    } \
    _Pragma("unroll") \
    for (int tm = 0; tm < 3; ++tm) { \
        i32x2 d_; \
        d_.x = (int)((pa_[tm][0] >> 16) | (pa_[tm][1] & 0xffff0000u)); \
        d_.y = (int)((pa_[tm][2] >> 16) | (pa_[tm][3] & 0xffff0000u)); \
        *(i32x2*)(smem + aW[PW] + 6144 + tm * 2048) = d_; \
    } \
} while (0)

#define MSTEP(TW, TE, PAR) \
    _Pragma("unroll") \
    for (int ks = 0; ks < 2; ++ks) { \
        acc00 = MFMA_BF16(Areg[PAR][0][TW][ks], Bf[0][TE][ks], acc00, 0, 0, 0); \
        acc01 = MFMA_BF16(Areg[PAR][1][TW][ks], Bf[0][TE][ks], acc01, 0, 0, 0); \
        acc10 = MFMA_BF16(Areg[PAR][0][TW][ks], Bf[1][TE][ks], acc10, 0, 0, 0); \
        acc11 = MFMA_BF16(Areg[PAR][1][TW][ks], Bf[1][TE][ks], acc11, 0, 0, 0); \
    }

#define SITE_BODY(S, II, PAR, DO_SCALE, DO_MAX) do { \
    PREFETCH_A((S) + 1, (PAR) ^ 1); \
    bf16x8 Bf[2][3][2]; \
    _Pragma("unroll") for (int gg = 0; gg < 2; ++gg) \
    _Pragma("unroll") for (int tm = 0; tm < 3; ++tm) \
    _Pragma("unroll") for (int ks = 0; ks < 2; ++ks) \
        Bf[gg][tm][ks] = *(const bf16x8*)(smem + aB[PAR][ks] + (gg * 3 + tm) * 2048); \
    f32x4 acc00 = {0.f,0.f,0.f,0.f}, acc01 = {0.f,0.f,0.f,0.f}; \
    f32x4 acc10 = {0.f,0.f,0.f,0.f}, acc11 = {0.f,0.f,0.f,0.f}; \
    MSTEP(2,0,PAR) MSTEP(1,1,PAR) MSTEP(0,2,PAR) \
    MSTEP(1,0,PAR) MSTEP(0,1,PAR) MSTEP(0,0,PAR) \
    const bool v0_ = ((mwa >> (II)) & 1u) != 0u; \
    const bool v1_ = ((mwb >> (II)) & 1u) != 0u; \
    eg0.x = v0_ ? acc01.x : acc00.x;  eg0.y = v0_ ? acc01.y : acc00.y; \
    eg0.z = v0_ ? acc01.z : acc00.z;  eg0.w = v0_ ? acc01.w : acc00.w; \
    eg1.x = v1_ ? acc11.x : acc10.x;  eg1.y = v1_ ? acc11.y : acc10.y; \
    eg1.z = v1_ ? acc11.z : acc10.z;  eg1.w = v1_ ? acc11.w : acc10.w; \
    if (DO_SCALE) { \
        f32x4 m4a = *(const f32x4*)(smem + RED_OFF + lb * 16); \
        f32x4 m4b = *(const f32x4*)(smem + RED_OFF + 256 + lb * 16); \
        const float ma = fmaxf(fmaxf(m4a.x, m4a.y), fmaxf(m4a.z, m4a.w)); \
        const float mb = fmaxf(fmaxf(m4b.x, m4b.y), fmaxf(m4b.z, m4b.w)); \
        const int ea = (__float_as_int(ma) >> 23) & 255; \
        const int eb = (__float_as_int(mb) >> 23) & 255; \
        const float sa = __int_as_float((254 - ea) << 23); \
        const float sb = __int_as_float((254 - eb) << 23); \
        ls0 += (float)(ea - 127) * 0.6931471805599453f; \
        ls1 += (float)(eb - 127) * 0.6931471805599453f; \
        eg0.x *= sa; eg0.y *= sa; eg0.z *= sa; eg0.w *= sa; \
        eg1.x *= sb; eg1.y *= sb; eg1.z *= sb; eg1.w *= sb; \
    } \
    if (DO_MAX) { \
        float ma = fmaxf(fmaxf(fabsf(eg0.x), fabsf(eg0.y)), fmaxf(fabsf(eg0.z), fabsf(eg0.w))); \
        float mb = fmaxf(fmaxf(fabsf(eg1.x), fabsf(eg1.y)), fmaxf(fabsf(eg1.z), fabsf(eg1.w))); \
        ma = fmaxf(ma, __shfl_xor(ma, 16)); ma = fmaxf(ma, __shfl_xor(ma, 32)); \
        mb = fmaxf(mb, __shfl_xor(mb, 16)); mb = fmaxf(mb, __shfl_xor(mb, 32)); \
        if (lg == 0) { \
            *(float*)(smem + RED_OFF + lb * 16 + jt * 4) = ma; \
            *(float*)(smem + RED_OFF + 256 + lb * 16 + jt * 4) = mb; \
        } \
    } \
    PUBLISH((PAR) ^ 1); \
    __syncthreads(); \
} while (0)

#define RUN_CHUNK(CB, MWE0, MWE1, CNT, SC0, MXE) { \
    const uint mwa = (MWE0), mwb = (MWE1); \
    _Pragma("unroll 1") \
    for (int i2 = 0; i2 < (CNT); i2 += 2) { \
        SITE_BODY((CB) * 32 + i2,     i2,     0, ((SC0) && i2 == 0),           false); \
        SITE_BODY((CB) * 32 + i2 + 1, i2 + 1, 1, false, ((MXE) && i2 == (CNT) - 2)); \
    } \
}

__global__ __launch_bounds__(256, 1) void mps_main(
    const int*   __restrict__ cfg,
    const float* __restrict__ left,
    const float* __restrict__ right,
    const char*  __restrict__ ws,
    float*       __restrict__ out)
{
    extern __shared__ __align__(16) char smem[];
    const int t  = threadIdx.x;
    const int w  = t >> 6, l = t & 63;
    const int lg = l >> 4, lb = l & 15;
    const int jt = w;                       // 4 waves = 4 j-tiles
    const int bbase = blockIdx.x * 32;
    const int b0 = bbase + lb, b1 = bbase + 16 + lb;

    // per-lane precomputed offsets
    int aG[2][3][2];                        // global fragment offsets within a site
    #pragma unroll
    for (int vv = 0; vv < 2; ++vv)
        #pragma unroll
        for (int tm = 0; tm < 3; ++tm)
            #pragma unroll
            for (int ks = 0; ks < 2; ++ks)
                aG[vv][tm][ks] = (((vv*3+tm)*2 + ks)*4 + jt) * 1024 + l * 16;

    int aB[2][2], aW[2];
    {
        const int key = lb & 7;
        const int s0 = ((0 + lg) ^ key) * 16;
        const int s1 = ((4 + lg) ^ key) * 16;
        aB[0][0] = lb * 128 + s0;          aB[0][1] = lb * 128 + s1;
        aB[1][0] = aB[0][0] + EBUF_SZ;     aB[1][1] = aB[0][1] + EBUF_SZ;
        aW[0] = lb * 128 + (((jt * 2 + (lg >> 1)) ^ key) * 16) + (lg & 1) * 8;
        aW[1] = aW[0] + EBUF_SZ;
    }

    bf16x8 Areg[2][2][3][2];                // [dbuf][v][term][ks] = 96 VGPR
    float ls0 = 0.f, ls1 = 0.f;
    f32x4 eg0 = {0.f,0.f,0.f,0.f}, eg1 = {0.f,0.f,0.f,0.f};

    PREFETCH_A(0, 0);                       // site-0 W fragments -> registers

    const uint* mp = (const uint*)(ws + WMASK_OFF);
    uint4 vmg0 = *(const uint4*)(mp + (size_t)b0 * 4);
    uint4 vmg1 = *(const uint4*)(mp + (size_t)b1 * 4);
    const int c00 = cfg[b0 * NSITES], c01 = cfg[b1 * NSITES];
    const int jout = jt * 16 + lg * 4;
    #pragma unroll
    for (int r = 0; r < 4; ++r) {
        eg0[r] = left[c00 * BOND + jout + r];
        eg1[r] = left[c01 * BOND + jout + r];
    }
    PUBLISH(0);
    __syncthreads();

    RUN_CHUNK(0, vmg0.x, vmg1.x, 32, false, true)
    RUN_CHUNK(1, vmg0.y, vmg1.y, 32, true,  true)
    RUN_CHUNK(2, vmg0.z, vmg1.z, 32, true,  true)
    RUN_CHUNK(3, vmg0.w, vmg1.w, 30, true,  false)

    // ---- epilogue: contract with right tensor, reduce across waves ----
    {
        const int vl0 = cfg[b0 * NSITES + 127], vl1 = cfg[b1 * NSITES + 127];
        float p0 = eg0.x * right[(jout + 0) * 2 + vl0] + eg0.y * right[(jout + 1) * 2 + vl0]
                 + eg0.z * right[(jout + 2) * 2 + vl0] + eg0.w * right[(jout + 3) * 2 + vl0];
        float p1 = eg1.x * right[(jout + 0) * 2 + vl1] + eg1.y * right[(jout + 1) * 2 + vl1]
                 + eg1.z * right[(jout + 2) * 2 + vl1] + eg1.w * right[(jout + 3) * 2 + vl1];
        p0 += __shfl_xor(p0, 16); p0 += __shfl_xor(p0, 32);
        p1 += __shfl_xor(p1, 16); p1 += __shfl_xor(p1, 32);
        if (lg == 0) {
            *(float*)(smem + RED_OFF + lb * 16 + jt * 4) = p0;
            *(float*)(smem + RED_OFF + 256 + lb * 16 + jt * 4) = p1;
        }
    }
    __syncthreads();
    if (w == 0 && l < 16) {
        f32x4 q0 = *(const f32x4*)(smem + RED_OFF + lb * 16);
        f32x4 q1 = *(const f32x4*)(smem + RED_OFF + 256 + lb * 16);
        const float s0 = (q0.x + q0.y) + (q0.z + q0.w);
        const float s1 = (q1.x + q1.y) + (q1.z + q1.w);
        out[b0] = 2.0f * (ls0 + logf(fmaxf(fabsf(s0), 1e-30f)));
        out[b1] = 2.0f * (ls1 + logf(fmaxf(fabsf(s1), 1e-30f)));
    }
}

// ================= fallback fp32 kernel (R0, known-good) =================
#define WPB     16
#define TPB     (WPB * 64)
#define SITE_ELTS (BOND * 2 * BOND)

__global__ __launch_bounds__(TPB, 2) void mps_logamp_fp32(
    const int*   __restrict__ cfg, const float* __restrict__ left,
    const float* __restrict__ bulk, const float* __restrict__ right,
    float* __restrict__ out)
{
    __shared__ float Abuf[2][SITE_ELTS];
    __shared__ float envs[WPB][BOND];
    __shared__ int   cfgs[WPB * NSITES];
    const int t = threadIdx.x;
    const int w = t >> 6, l = t & 63;
    const int bbase = blockIdx.x * WPB;
    const int b = bbase + w;
    cfgs[t] = cfg[bbase * NSITES + t];
    cfgs[t + TPB] = cfg[bbase * NSITES + t + TPB];
    { const float4* src = (const float4*)bulk; float4* dst = (float4*)(&Abuf[0][0]);
      dst[t] = src[t]; dst[t + TPB] = src[t + TPB]; }
    __syncthreads();
    const int c0 = cfgs[w * NSITES];
    float e = left[c0 * BOND + l];
    float m = fabsf(e);
    #pragma unroll
    for (int k = 32; k; k >>= 1) m = fmaxf(m, __shfl_xor(m, k));
    m = fmaxf(m, 1e-30f);
    e = e / m;
    float ls = logf(m);
    envs[w][l] = e;
    for (int s = 0; s < NBULK; ++s) {
        const int cur = s & 1, nxt = cur ^ 1;
        const bool pf = (s + 1 < NBULK);
        float4 p0, p1;
        if (pf) { const float4* src = (const float4*)(bulk + (size_t)(s + 1) * SITE_ELTS);
                  p0 = src[t]; p1 = src[t + TPB]; }
        const int v = cfgs[w * NSITES + (s + 1)];
        const float* Ap = &Abuf[cur][v * BOND + l];
        const float* ev = &envs[w][0];
        float acc = 0.0f;
        #pragma unroll
        for (int i = 0; i < BOND; i += 4) {
            const float4 e4 = *(const float4*)(ev + i);
            acc = fmaf(e4.x, Ap[(i + 0) * 128], acc);
            acc = fmaf(e4.y, Ap[(i + 1) * 128], acc);
            acc = fmaf(e4.z, Ap[(i + 2) * 128], acc);
            acc = fmaf(e4.w, Ap[(i + 3) * 128], acc);
        }
        float mm = fabsf(acc);
        #pragma unroll
        for (int k = 32; k; k >>= 1) mm = fmaxf(mm, __shfl_xor(mm, k));
        mm = fmaxf(mm, 1e-30f);
        acc = acc / mm;
        ls += logf(mm);
        if (pf) { float4* dst = (float4*)(&Abuf[nxt][0]); dst[t] = p0; dst[t + TPB] = p1; }
        envs[w][l] = acc;
        e = acc;
        __syncthreads();
    }
    const int vl = cfgs[w * NSITES + (NSITES - 1)];
    float p = e * right[l * 2 + vl];
    #pragma unroll
    for (int k = 32; k; k >>= 1) p += __shfl_xor(p, k);
    const float am = fmaxf(fabsf(p), 1e-30f);
    if (l == 0) out[b] = 2.0f * (ls + logf(am));
}

extern "C" void kernel_launch(void* const* d_in, const int* in_sizes, int n_in,
                              void* d_out, int out_size, void* d_ws, size_t ws_size,
                              hipStream_t stream) {
    const int*   cfg   = (const int*)d_in[0];
    const float* left  = (const float*)d_in[1];
    const float* bulk  = (const float*)d_in[2];
    const float* right = (const float*)d_in[3];
    float*       out   = (float*)d_out;

    if (ws_size >= WS_NEED) {
        hipLaunchKernelGGL(prep_w, dim3(NBULK), dim3(256), 0, stream,
                           bulk, (char*)d_ws);
        hipLaunchKernelGGL(prep_mask, dim3(BATCH / 2), dim3(256), 0, stream,
                           cfg, (uint*)((char*)d_ws + WMASK_OFF));
        hipLaunchKernelGGL(mps_main, dim3(BATCH / 32), dim3(256), SMEM_SZ, stream,
                           cfg, left, right, (const char*)d_ws, out);
    } else {
        hipLaunchKernelGGL(mps_logamp_fp32, dim3(BATCH / WPB), dim3(TPB), 0, stream,
                           cfg, left, bulk, right, out);
    }
}